// Round 6
// baseline (429.753 us; speedup 1.0000x reference)
//
#include <hip/hip_runtime.h>
#include <stdint.h>

// Hard voxelization, MI355X. f32x4 points -> f32 concat out:
//   voxels[60000,32,4], coors[60000,3](z,y,x), npv[60000], voxel_num[1].
//
// R17 forensics: hand-rolled barrier got k_all 728 -> k_rest 288us, but each
// barrier still costs ~85us. Cause: spinners poll with ACQUIRE agent loads --
// every poll emits a cache invalidate (buffer_inv) and hits ONE release line;
// 767 leaders x ~1/us = invalidate storm that serializes the wake AND evicts
// the working blocks' L2 (bitmap/pflat reads go cold). R18 barrier v2:
//   arrive  = RELAXED atomic store to the block's OWN slot (no RMW, no shared
//             line, write-through at 4B granularity),
//   detect  = block 0 sweeps 768 slots with RELAXED loads (no invalidates),
//             one __threadfence() for the acquire edge,
//   release = fan-out to 32 padded flag lines; spinners poll RELAXED +
//             s_sleep(8), one __threadfence() per block after the flip.
// Scan runs in barrier-2's winner section (block 0). k_zero_partials merged
// into k_init. 2 dispatches total; host falls back to the proven R15
// multi-kernel path if the cooperative launch is rejected.

#define GX 1024
#define GY 1024
#define GZ 40
#define NVOXEL (GX * GY * GZ)                 // 41,943,040
#define MAXV 60000
#define MAXP 32
#define HBITS 21
#define HSIZE (1u << HBITS)
#define HMASK (HSIZE - 1u)
#define CANDBIT (1 << 30)
#define FLATMASK (CANDBIT - 1)
#define TB 256
#define KEARLY 131072
#define NBE (KEARLY / TB)                     // 512 early blocks
#define NBITW (NVOXEL / 32)                   // 1,310,720 bitmap words
#define GRID_BLKS 768                         // cooperative grid (validated R16)
#define NREL 32                               // release fan-out lines
#define BAR_INTS (GRID_BLKS + NREL * 16)      // 1280 ints per barrier instance
#define NBAR 6
#define EMPTY64 0xFFFFFFFFFFFFFFFFull

#define OFF_COORS ((size_t)MAXV * MAXP * 4)            // 7,680,000
#define OFF_NPV   (OFF_COORS + (size_t)MAXV * 3)       // 7,860,000
#define OFF_VNUM  (OFF_NPV + (size_t)MAXV)             // 7,920,000

typedef unsigned long long u64;

__device__ __forceinline__ unsigned hashf(int flat) {
    return ((unsigned)flat * 2654435761u) >> (32 - HBITS);
}

__device__ __forceinline__ int voxel_flat(float4 pt) {
    // identical IEEE f32 math to reference
    float fx = floorf((pt.x + 51.2f) / 0.1f);
    float fy = floorf((pt.y + 51.2f) / 0.1f);
    float fz = floorf((pt.z + 5.0f) / 0.2f);
    int cx = (int)fx, cy = (int)fy, cz = (int)fz;
    bool valid = (fx >= 0.f) & (cx < GX) & (fy >= 0.f) & (cy < GY) & (fz >= 0.f) & (cz < GZ);
    return valid ? (cx * GY + cy) * GZ + cz : -1;
}

// ======== barrier v2: slot-arrive / block0-detect / fanout-release ========
// Instance layout (ints): arrive[GRID_BLKS], then NREL flag lines 16 ints
// apart. Single-use per launch; zeroed by k_init (kernel-boundary flush makes
// the zeros globally visible before k_rest starts).
__device__ __forceinline__ void bar_signal(int* inst) {
    __syncthreads();
    __threadfence();                                     // release prior writes (wb)
    if (threadIdx.x == 0)
        __hip_atomic_store(&inst[blockIdx.x], 1, __ATOMIC_RELAXED,
                           __HIP_MEMORY_SCOPE_AGENT);
}
__device__ __forceinline__ void bar_detect(int* inst) {  // block 0 only
    __shared__ int nmiss;
    const int t = threadIdx.x;
    for (int sweep = 0; sweep < (1 << 22); sweep++) {    // bounded: hang-proof
        if (t == 0) nmiss = 0;
        __syncthreads();
        int miss = 0;
        #pragma unroll
        for (int k = 0; k < GRID_BLKS / TB; k++) {       // 3 slots/thread
            if (__hip_atomic_load(&inst[t + k * TB], __ATOMIC_RELAXED,
                                  __HIP_MEMORY_SCOPE_AGENT) == 0) miss = 1;
        }
        if (miss) nmiss = 1;                             // racy-OK (all write 1)
        __syncthreads();
        if (nmiss == 0) break;
        __builtin_amdgcn_s_sleep(8);
    }
    __threadfence();                                     // acquire edge (inv)
}
__device__ __forceinline__ void bar_open(int* inst) {    // block 0 only
    __threadfence();                                     // publish winner work (wb)
    for (int r = threadIdx.x; r < NREL; r += TB)
        __hip_atomic_store(&inst[GRID_BLKS + r * 16], 1, __ATOMIC_RELAXED,
                           __HIP_MEMORY_SCOPE_AGENT);
    __syncthreads();
}
__device__ __forceinline__ void bar_spin(int* inst) {    // blocks != 0
    if (threadIdx.x == 0) {
        int* flag = &inst[GRID_BLKS + (blockIdx.x & (NREL - 1)) * 16];
        for (int sp = 0; sp < (1 << 24); sp++) {         // bounded: hang-proof
            if (__hip_atomic_load(flag, __ATOMIC_RELAXED,
                                  __HIP_MEMORY_SCOPE_AGENT) != 0) break;
            __builtin_amdgcn_s_sleep(8);
        }
    }
    __syncthreads();
    __threadfence();                                     // acquire edge (inv)
}
__device__ __forceinline__ void gbar(int* inst) {
    bar_signal(inst);
    if (blockIdx.x == 0) { bar_detect(inst); bar_open(inst); }
    else bar_spin(inst);
}

// ---- exact insert path (R12 semantics): 1 CAS typ.; returns pflat value ----
__device__ __forceinline__ int build_insert(int p, int flat, u64* __restrict__ h64,
                                            unsigned char* __restrict__ contested,
                                            int* __restrict__ nvox,
                                            unsigned* __restrict__ bitmap,
                                            int count_wins) {
    u64 want = ((u64)(unsigned)flat << 32) | (unsigned)p;
    unsigned slot = hashf(flat);
    int cand = 0, won = 0;
    for (int probe = 0; probe < 4096; probe++) {          // bounded: hang-proof
        u64 cur = atomicCAS(&h64[slot], EMPTY64, want);
        if (cur == EMPTY64) { cand = 1; won = 1; break; } // insert winner (new voxel)
        if ((unsigned)(cur >> 32) == (unsigned)flat) {    // existing voxel
            if ((unsigned)cur > (unsigned)p) {
                u64 old = atomicMin(&h64[slot], want);    // key equal -> compares rep
                unsigned oldrep = (unsigned)old;
                if (oldrep > (unsigned)p) {               // we really lowered it
                    contested[oldrep] = 1;                // previous holder dethroned
                    cand = 1;
                }
            }
            break;
        }
        slot = (slot + 1u) & HMASK;
    }
    if (won) {
        atomicOr(&bitmap[(unsigned)flat >> 5], 1u << (flat & 31));  // voxel present
        if (count_wins) atomicAdd(nvox, 1);               // wave-aggregated
    }
    return flat | (cand ? CANDBIT : 0);
}

// ---- dup registration: flat -> h64 rep -> popcount rank -> dupcnt/list ----
__device__ __forceinline__ void register_dup(int flat, int i,
                                             const u64* __restrict__ h64,
                                             const u64* __restrict__ flagbits,
                                             const int* __restrict__ partials,
                                             int* __restrict__ dupcnt,
                                             int* __restrict__ list) {
    unsigned slot = hashf(flat);
    unsigned rep = 0xFFFFFFFFu;
    for (int probe = 0; probe < 4096; probe++) {     // read-only, cache-hot
        u64 cur = h64[slot];
        if ((unsigned)(cur >> 32) == (unsigned)flat) { rep = (unsigned)cur; break; }
        if (cur == EMPTY64) break;
        slot = (slot + 1u) & HMASK;
    }
    if (rep == 0xFFFFFFFFu) return;
    int br = (int)(rep >> 8);                        // rep's 256-block
    int lb = (int)(rep & 255u);
    int dvid = partials[br];
    int wb = br * 4, nw = lb >> 6;
    for (int q = 0; q < nw; q++) dvid += (int)__popcll(flagbits[wb + q]);
    int tail = lb & 63;
    if (tail) dvid += (int)__popcll(flagbits[wb + nw] & ((1ull << tail) - 1ull));
    if (dvid < MAXV) {
        int pos = atomicAdd(&dupcnt[dvid], 1);
        if (pos < MAXP - 1) list[dvid * (MAXP - 1) + pos] = i;
    }
}

// ---- init (normal launch): h64, bitmap, contested, dupcnt/repidx, coors,
//      partials, nvox/dcnt, barrier region ----
__global__ void k_init(u64* __restrict__ h64, unsigned char* __restrict__ contested,
                       int* __restrict__ dupcnt, int* __restrict__ repidx,
                       int n, int nbp, float* __restrict__ oF,
                       int* __restrict__ nvox, unsigned* __restrict__ bitmap,
                       unsigned* __restrict__ dcnt, int* __restrict__ bars,
                       int* __restrict__ partials) {
    int i = blockIdx.x * blockDim.x + threadIdx.x;
    int stride = gridDim.x * blockDim.x;
    if (i == 0) { *nvox = 0; *dcnt = 0; }
    for (int j = i; j < (int)HSIZE; j += stride) h64[j] = EMPTY64;
    for (int j = i; j < NBITW; j += stride) bitmap[j] = 0u;
    int nw = (n + 3) / 4;
    unsigned* c4 = (unsigned*)contested;
    for (int j = i; j < nw; j += stride) c4[j] = 0;
    for (int j = i; j < MAXV; j += stride) { dupcnt[j] = 0; repidx[j] = -1; }
    for (int j = i; j < MAXV * 3; j += stride) oF[OFF_COORS + j] = 0.f;
    for (int j = i; j < nbp; j += stride) partials[j] = 0;
    for (int j = i; j < NBAR * BAR_INTS; j += stride) bars[j] = 0;
}

// =================== fused cooperative kernel (post-init) ===================
__global__ __launch_bounds__(TB, 4) void k_rest(const float4* __restrict__ pts,
                                                int n, int nbp,
                                                u64* __restrict__ h64,
                                                unsigned* __restrict__ bitmap,
                                                unsigned char* __restrict__ contested,
                                                int* __restrict__ pflat,
                                                u64* __restrict__ flagbits,
                                                int* __restrict__ partials,
                                                int* __restrict__ repidx,
                                                int* __restrict__ dupcnt,
                                                int* __restrict__ list,
                                                u64* __restrict__ latedup,
                                                int* __restrict__ nvox,
                                                unsigned* __restrict__ dcnt,
                                                int* __restrict__ bars,
                                                float4* __restrict__ outVox,
                                                float* __restrict__ oF) {
    const int t = threadIdx.x;
    const int gid = blockIdx.x * TB + t;
    const int gsz = GRID_BLKS * TB;
    __shared__ int sh[TB];

    // ---- S1 build_early: first min(n,KEARLY) pts, full insert + bitmap ----
    {
        int nE = n < KEARLY ? n : KEARLY;
        for (int p = gid; p < nE; p += gsz) {
            float4 pt = pts[p];
            int flat = voxel_flat(pt);
            if (flat < 0) { pflat[p] = -1; continue; }
            pflat[p] = build_insert(p, flat, h64, contested, nvox, bitmap, 1);
        }
    }
    gbar(bars + 0 * BAR_INTS);                           // B0

    const bool fast = (*((volatile int*)nvox) >= MAXV);  // grid-uniform after B0
    const int npbF = fast ? (nbp < NBE ? nbp : NBE) : nbp;

    // ---- S2 ----
    if (fast) {
        // late probe: >=MAXV voxels exist with reps < KEARLY <= p, so a voxel
        // first seen here would get vid >= MAXV => dropped. Only dup-of-early
        // matters; bitmap answers membership exactly. No pflat/h64 traffic.
        for (int p = KEARLY + gid; p < n; p += gsz) {
            float4 pt = pts[p];
            int flat = voxel_flat(pt);
            if (flat < 0) continue;
            unsigned wv = bitmap[(unsigned)flat >> 5];
            if (wv & (1u << (flat & 31))) {
                unsigned pos = atomicAdd(dcnt, 1u);
                if (pos < (unsigned)(n - KEARLY))
                    latedup[pos] = ((u64)(unsigned)flat << 32) | (unsigned)p;
            }
        }
        // flags for early point-blocks (late points can never be reps)
        for (int pb = blockIdx.x; pb < npbF; pb += GRID_BLKS) {
            int i = pb * TB + t;
            int pred = 0;
            if (i < n) {
                int pf = pflat[i];
                pred = (pf >= 0) && (pf & CANDBIT) && !contested[i];
            }
            u64 m = __ballot(pred);
            if ((t & 63) == 0) {
                flagbits[pb * 4 + (t >> 6)] = m;
                atomicAdd(&partials[pb], (int)__popcll(m));
            }
        }
    } else {
        // fallback: exact R12 insert for late points, then flags over ALL
        for (int p = KEARLY + gid; p < n; p += gsz) {
            float4 pt = pts[p];
            int flat = voxel_flat(pt);
            if (flat < 0) { pflat[p] = -1; continue; }
            pflat[p] = build_insert(p, flat, h64, contested, nvox, bitmap, 0);
        }
        gbar(bars + 1 * BAR_INTS);                       // Bfb (fallback only)
        for (int pb = blockIdx.x; pb < nbp; pb += GRID_BLKS) {
            int i = pb * TB + t;
            int pred = 0;
            if (i < n) {
                int pf = pflat[i];
                pred = (pf >= 0) && (pf & CANDBIT) && !contested[i];
            }
            u64 m = __ballot(pred);
            if ((t & 63) == 0) {
                flagbits[pb * 4 + (t >> 6)] = m;
                atomicAdd(&partials[pb], (int)__popcll(m));
            }
        }
    }

    // ---- B1 + scan in winner section: exclusive prefix over npbF partials ----
    {
        int* i1 = bars + 2 * BAR_INTS;
        bar_signal(i1);
        if (blockIdx.x == 0) {
            bar_detect(i1);                              // fence: partials fresh
            int E = (npbF + TB - 1) / TB;                // 2 fast / 19 fallback
            int s = 0;
            for (int k = 0; k < E; k++) {
                int idx = t * E + k;
                if (idx < npbF) s += partials[idx];
            }
            sh[t] = s;
            __syncthreads();
            for (int off = 1; off < TB; off <<= 1) {
                int add = (t >= off) ? sh[t - off] : 0;
                __syncthreads();
                sh[t] += add;
                __syncthreads();
            }
            int run = sh[t] - s;                         // exclusive base
            for (int k = 0; k < E; k++) {
                int idx = t * E + k;
                if (idx < npbF) { int tmp = partials[idx]; partials[idx] = run; run += tmp; }
            }
            if (t == TB - 1) {
                int total = sh[TB - 1];
                if (total > MAXV) total = MAXV;
                oF[OFF_VNUM] = (float)total;             // voxel_num
            }
            __syncthreads();
            bar_open(i1);                                // fence publishes scan
        } else {
            bar_spin(i1);
        }
    }

    // ---- S3 finish: reps->coors/repidx, per-point dups; + latedup drain ----
    for (int pb = blockIdx.x; pb < npbF; pb += GRID_BLKS) {
        int i = pb * TB + t;
        if (i >= n) continue;
        int lane = t & 63, w = t >> 6;
        u64 w0 = flagbits[pb * 4 + 0];
        u64 w1 = flagbits[pb * 4 + 1];
        u64 w2 = flagbits[pb * 4 + 2];
        u64 w3 = flagbits[pb * 4 + 3];
        u64 myw = (w == 0) ? w0 : (w == 1) ? w1 : (w == 2) ? w2 : w3;
        int bit = (int)((myw >> lane) & 1);
        int pf = pflat[i];
        if (bit) {                                       // first occurrence (rep)
            int wbase = (w > 0 ? __popcll(w0) : 0) + (w > 1 ? __popcll(w1) : 0)
                      + (w > 2 ? __popcll(w2) : 0);
            int vid = partials[pb] + wbase + (int)__popcll(myw & ((1ull << lane) - 1ull));
            if (vid < MAXV) {
                int flat = pf & FLATMASK;
                int zc = flat % GZ;
                int t2 = flat / GZ;
                int yc = t2 % GY;
                int xc = t2 / GY;
                size_t cOff = OFF_COORS + (size_t)vid * 3;
                oF[cOff + 0] = (float)zc;
                oF[cOff + 1] = (float)yc;
                oF[cOff + 2] = (float)xc;
                repidx[vid] = i;
            }
        } else if (pf >= 0) {                            // non-rep valid
            register_dup(pf & FLATMASK, i, h64, flagbits, partials, dupcnt, list);
        }
    }
    {
        unsigned cnt = *((volatile unsigned*)dcnt);      // 0 in fallback
        unsigned cap = (n > KEARLY) ? (unsigned)(n - KEARLY) : 0u;
        if (cnt > cap) cnt = cap;
        for (unsigned idx = (unsigned)gid; idx < cnt; idx += (unsigned)gsz) {
            u64 e = latedup[idx];
            register_dup((int)(e >> 32), (int)(unsigned)e,
                         h64, flagbits, partials, dupcnt, list);
        }
    }
    gbar(bars + 3 * BAR_INTS);                           // B2

    // ---- S4 emit: thread-per-row, fully coalesced voxels store; npv ----
    for (int g2 = gid; g2 < MAXV * MAXP; g2 += gsz) {
        int vid = g2 >> 5;
        int r = g2 & 31;
        int ri = repidx[vid];
        int dc = dupcnt[vid];
        int d = dc < (MAXP - 1) ? dc : (MAXP - 1);
        int m = (ri >= 0) ? (1 + d) : 0;
        if (r == 0) oF[OFF_NPV + vid] = (float)m;
        float4 row = make_float4(0.f, 0.f, 0.f, 0.f);
        if (r == 0 && m > 0) {
            row = pts[ri];                               // rep = provably min index
        } else if (r < m) {                              // dup rows, ascending index
            const int* lst = &list[vid * (MAXP - 1)];
            int target = r - 1, pick = -1;
            for (int a = 0; a < d; a++) {
                int e = lst[a];
                int rk = 0;
                for (int bq = 0; bq < d; bq++) rk += (lst[bq] < e);
                if (rk == target) pick = e;
            }
            row = pts[pick];
        }
        outVox[(size_t)vid * MAXP + r] = row;            // coalesced 16B stores
    }
}

// =================== legacy multi-kernel fallback path ===================
__global__ __launch_bounds__(TB) void k_build_early(const float4* __restrict__ pts, int nE,
                                                    u64* __restrict__ h64,
                                                    int* __restrict__ pflat,
                                                    unsigned char* __restrict__ contested,
                                                    int* __restrict__ nvox,
                                                    unsigned* __restrict__ bitmap) {
    int p = blockIdx.x * blockDim.x + threadIdx.x;
    if (p >= nE) return;
    float4 pt = pts[p];
    int flat = voxel_flat(pt);
    if (flat < 0) { pflat[p] = -1; return; }
    pflat[p] = build_insert(p, flat, h64, contested, nvox, bitmap, 1);
}

__global__ __launch_bounds__(TB) void k_build_late(const float4* __restrict__ pts, int n,
                                                   u64* __restrict__ h64,
                                                   int* __restrict__ pflat,
                                                   unsigned char* __restrict__ contested,
                                                   int* __restrict__ nvox,
                                                   unsigned* __restrict__ bitmap,
                                                   u64* __restrict__ latedup,
                                                   unsigned* __restrict__ dcnt) {
    int p = KEARLY + blockIdx.x * blockDim.x + threadIdx.x;
    if (p >= n) return;
    float4 pt = pts[p];
    int flat = voxel_flat(pt);
    if (*nvox < MAXV) {
        if (flat < 0) { pflat[p] = -1; return; }
        pflat[p] = build_insert(p, flat, h64, contested, nvox, bitmap, 0);
        return;
    }
    if (flat < 0) return;
    unsigned w = bitmap[(unsigned)flat >> 5];
    if (w & (1u << (flat & 31))) {
        unsigned pos = atomicAdd(dcnt, 1u);
        if (pos < (unsigned)(n - KEARLY))
            latedup[pos] = ((u64)(unsigned)flat << 32) | (unsigned)p;
    }
}

__global__ __launch_bounds__(TB) void k_flags(const int* __restrict__ pflat,
                                              const unsigned char* __restrict__ contested,
                                              int n, u64* __restrict__ flagbits,
                                              int* __restrict__ partials,
                                              const int* __restrict__ nvox) {
    __shared__ int ws[4];
    int b = blockIdx.x, t = threadIdx.x;
    int i = b * TB + t;
    int fastmode = (*nvox >= MAXV);
    int pred = 0;
    if (i < n && (b < NBE || !fastmode)) {
        int pf = pflat[i];
        pred = (pf >= 0) && (pf & CANDBIT) && !contested[i];
    }
    u64 m = __ballot(pred);
    int w = t >> 6, lane = t & 63;
    if (lane == 0) { flagbits[b * 4 + w] = m; ws[w] = __popcll(m); }
    __syncthreads();
    if (t == 0) partials[b] = ws[0] + ws[1] + ws[2] + ws[3];
}

__global__ __launch_bounds__(1024) void k_scan(int* __restrict__ partials, int npart,
                                               float* __restrict__ oF) {
    __shared__ int sh[1024];
    int t = threadIdx.x;
    int v[5];
    int s = 0;
    #pragma unroll
    for (int k = 0; k < 5; k++) {
        int idx = t * 5 + k;
        v[k] = (idx < npart) ? partials[idx] : 0;
        s += v[k];
    }
    sh[t] = s;
    __syncthreads();
    for (int off = 1; off < 1024; off <<= 1) {
        int add = (t >= off) ? sh[t - off] : 0;
        __syncthreads();
        sh[t] += add;
        __syncthreads();
    }
    int run = sh[t] - s;
    #pragma unroll
    for (int k = 0; k < 5; k++) {
        int idx = t * 5 + k;
        if (idx < npart) partials[idx] = run;
        run += v[k];
    }
    if (t == 1023) {
        int total = sh[1023];
        if (total > MAXV) total = MAXV;
        oF[OFF_VNUM] = (float)total;
    }
}

__global__ __launch_bounds__(TB) void k_finish(const u64* __restrict__ flagbits,
                                               const int* __restrict__ partials,
                                               const int* __restrict__ pflat,
                                               const u64* __restrict__ h64,
                                               int* __restrict__ repidx,
                                               int* __restrict__ dupcnt,
                                               int* __restrict__ list, int n,
                                               float* __restrict__ oF,
                                               const int* __restrict__ nvox,
                                               const u64* __restrict__ latedup,
                                               const unsigned* __restrict__ dcnt) {
    int b = blockIdx.x, t = threadIdx.x;
    int fastmode = (*nvox >= MAXV);
    if (fastmode && b >= NBE) {
        unsigned cnt = *dcnt;
        unsigned cap = (unsigned)(n - KEARLY);
        if (cnt > cap) cnt = cap;
        unsigned idx = (unsigned)(b - NBE) * TB + t;
        if (idx < cnt) {
            u64 e = latedup[idx];
            register_dup((int)(e >> 32), (int)(unsigned)e,
                         h64, flagbits, partials, dupcnt, list);
        }
        return;
    }
    int i = b * TB + t;
    if (i >= n) return;
    int lane = t & 63, w = t >> 6;
    u64 w0 = flagbits[b * 4 + 0];
    u64 w1 = flagbits[b * 4 + 1];
    u64 w2 = flagbits[b * 4 + 2];
    u64 w3 = flagbits[b * 4 + 3];
    u64 myw = (w == 0) ? w0 : (w == 1) ? w1 : (w == 2) ? w2 : w3;
    int bit = (int)((myw >> lane) & 1);
    int pf = pflat[i];
    if (bit) {
        int wbase = (w > 0 ? __popcll(w0) : 0) + (w > 1 ? __popcll(w1) : 0)
                  + (w > 2 ? __popcll(w2) : 0);
        int vid = partials[b] + wbase + (int)__popcll(myw & ((1ull << lane) - 1ull));
        if (vid < MAXV) {
            int flat = pf & FLATMASK;
            int zc = flat % GZ;
            int t2 = flat / GZ;
            int yc = t2 % GY;
            int xc = t2 / GY;
            size_t cOff = OFF_COORS + (size_t)vid * 3;
            oF[cOff + 0] = (float)zc;
            oF[cOff + 1] = (float)yc;
            oF[cOff + 2] = (float)xc;
            repidx[vid] = i;
        }
    } else if (pf >= 0) {
        register_dup(pf & FLATMASK, i, h64, flagbits, partials, dupcnt, list);
    }
}

__global__ __launch_bounds__(TB) void k_emit(const float4* __restrict__ pts,
                                             const int* __restrict__ repidx,
                                             const int* __restrict__ dupcnt,
                                             const int* __restrict__ list,
                                             float4* __restrict__ outVox,
                                             float* __restrict__ oF) {
    int gid = blockIdx.x * TB + threadIdx.x;
    int vid = gid >> 5;
    if (vid >= MAXV) return;
    int r = gid & 31;
    int ri = repidx[vid];
    int dc = dupcnt[vid];
    int d = dc < (MAXP - 1) ? dc : (MAXP - 1);
    int m = (ri >= 0) ? (1 + d) : 0;
    if (r == 0) oF[OFF_NPV + vid] = (float)m;
    float4 row = make_float4(0.f, 0.f, 0.f, 0.f);
    if (r == 0 && m > 0) {
        row = pts[ri];
    } else if (r < m) {
        const int* lst = &list[vid * (MAXP - 1)];
        int target = r - 1, pick = -1;
        for (int a = 0; a < d; a++) {
            int e = lst[a];
            int rk = 0;
            for (int bq = 0; bq < d; bq++) rk += (lst[bq] < e);
            if (rk == target) pick = e;
        }
        row = pts[pick];
    }
    outVox[(size_t)vid * MAXP + r] = row;
}

extern "C" void kernel_launch(void* const* d_in, const int* in_sizes, int n_in,
                              void* d_out, int out_size, void* d_ws, size_t ws_size,
                              hipStream_t stream) {
    int n = in_sizes[0] / 4;                       // 1,200,000
    const float4* pts = (const float4*)d_in[0];

    int tb = TB;
    int nbp = (n + tb - 1) / tb;                   // 4688
    int nwords = nbp * 4;

    // ws layout, ~45 MB
    char* base = (char*)d_ws;
    size_t o = 0;
    int* partials = (int*)(base + o);  o += ((size_t)nbp * 4 + 255) & ~(size_t)255;
    int* dupcnt   = (int*)(base + o);  o += (size_t)MAXV * 4;
    int* repidx   = (int*)(base + o);  o += (size_t)MAXV * 4;
    o = (o + 255) & ~(size_t)255;
    u64* flagbits = (u64*)(base + o);  o += (size_t)nwords * 8;
    o = (o + 255) & ~(size_t)255;
    unsigned char* contested = (unsigned char*)(base + o);  o += ((size_t)n + 255) & ~(size_t)255;
    u64* h64      = (u64*)(base + o);  o += (size_t)HSIZE * 8;
    int* pflat    = (int*)(base + o);  o += (size_t)n * 4;
    int* list     = (int*)(base + o);  o += (size_t)MAXV * (MAXP - 1) * 4;
    o = (o + 255) & ~(size_t)255;
    unsigned* bitmap = (unsigned*)(base + o);  o += (size_t)NBITW * 4;
    o = (o + 255) & ~(size_t)255;
    u64* latedup  = (u64*)(base + o);  o += (size_t)(n > KEARLY ? n - KEARLY : 1) * 8;
    o = (o + 255) & ~(size_t)255;
    int* nvox     = (int*)(base + o);  o += 256;
    unsigned* dcnt = (unsigned*)(base + o);  o += 256;
    int* bars     = (int*)(base + o);  o += ((size_t)NBAR * BAR_INTS * 4 + 255) & ~(size_t)255;

    float* oF = (float*)d_out;
    float4* outVox = (float4*)d_out;

    // dispatch 1: init (zeroes everything incl. partials + barrier region)
    k_init<<<2048, tb, 0, stream>>>(h64, contested, dupcnt, repidx, n, nbp, oF,
                                    nvox, bitmap, dcnt, bars, partials);

    // dispatch 2: fused cooperative remainder (3 barriers fast mode)
    void* args[] = { (void*)&pts, (void*)&n, (void*)&nbp, (void*)&h64,
                     (void*)&bitmap, (void*)&contested, (void*)&pflat,
                     (void*)&flagbits, (void*)&partials, (void*)&repidx,
                     (void*)&dupcnt, (void*)&list, (void*)&latedup,
                     (void*)&nvox, (void*)&dcnt, (void*)&bars,
                     (void*)&outVox, (void*)&oF };
    hipError_t err = hipLaunchCooperativeKernel((const void*)k_rest,
                                                dim3(GRID_BLKS), dim3(TB),
                                                args, 0, stream);
    if (err == hipSuccess) return;

    // fallback: proven R15 multi-kernel pipeline (init already ran)
    int nE = n < KEARLY ? n : KEARLY;
    int nbE = (nE + tb - 1) / tb;
    int nL = n - nE;

    k_build_early<<<nbE, tb, 0, stream>>>(pts, nE, h64, pflat, contested, nvox, bitmap);
    if (nL > 0)
        k_build_late<<<(nL + tb - 1) / tb, tb, 0, stream>>>(pts, n, h64, pflat,
                                                            contested, nvox, bitmap,
                                                            latedup, dcnt);
    k_flags<<<nbp, tb, 0, stream>>>(pflat, contested, n, flagbits, partials, nvox);
    k_scan<<<1, 1024, 0, stream>>>(partials, nbp, oF);
    k_finish<<<nbp, tb, 0, stream>>>(flagbits, partials, pflat, h64, repidx, dupcnt,
                                     list, n, oF, nvox, latedup, dcnt);
    k_emit<<<(MAXV * MAXP + tb - 1) / tb, tb, 0, stream>>>(pts, repidx, dupcnt, list,
                                                           outVox, oF);
}

// Round 7
// 149.530 us; speedup vs baseline: 2.8740x; 2.8740x over previous
//
#include <hip/hip_runtime.h>
#include <stdint.h>

// Hard voxelization, MI355X. f32x4 points -> f32 concat out:
//   voxels[60000,32,4], coors[60000,3](z,y,x), npv[60000], voxel_num[1].
//
// R16-R18 forensics: THREE in-kernel grid-sync implementations (cg::grid.sync
// 140us, ACQUIRE-poll 85us, RELAXED-poll 107us) all cost ~100us/sync on
// gfx950: ACQUIRE polls pay a cache-invalidate per poll; RELAXED polls go
// stale in the non-coherent per-XCD L2 until natural eviction. The HW command
// processor does the same wb/inv at kernel boundaries for ~8us. Fusion with
// grid barriers is structurally inferior -> abandoned.
// R19: proven R15 multi-kernel pipeline, minus 2 dispatches:
//   k_init -> k_build_early -> k_mid -> k_finish -> k_emit   (5 dispatches)
// k_mid runs {late bitmap-probe || flags-early || inline scan} in one kernel:
// both probe and flags depend only on build_early, and the scan is done by
// the LAST-arriving flags block (ticket atomicAdd; nobody spins). HBITS 21->18
// (2MB table, alpha 0.31 for ~81K early voxels): -14.6MB init, L2-hot
// reprobes. Fallback (nvox<MAXV, adversarial only) is self-contained in k_mid
// via one bounded RMW-poll barrier (atomicAdd(p,0) = coherence-point read, no
// cache pollution); grid 1024 = guaranteed resident at __launch_bounds__(256,4).

#define GX 1024
#define GY 1024
#define GZ 40
#define NVOXEL (GX * GY * GZ)                 // 41,943,040
#define MAXV 60000
#define MAXP 32
#define HBITS 18
#define HSIZE (1u << HBITS)                   // 262,144 slots = 2 MB
#define HMASK (HSIZE - 1u)
#define CANDBIT (1 << 30)
#define FLATMASK (CANDBIT - 1)
#define TB 256
#define KEARLY 131072
#define NBE (KEARLY / TB)                     // 512 early point-blocks
#define NBITW (NVOXEL / 32)                   // 1,310,720 bitmap words
#define MIDB 1024                             // k_mid grid (resident @ 4/CU)
#define NREL 32                               // fb-barrier release fan-out
#define EMPTY64 0xFFFFFFFFFFFFFFFFull

#define OFF_COORS ((size_t)MAXV * MAXP * 4)            // 7,680,000
#define OFF_NPV   (OFF_COORS + (size_t)MAXV * 3)       // 7,860,000
#define OFF_VNUM  (OFF_NPV + (size_t)MAXV)             // 7,920,000

typedef unsigned long long u64;

__device__ __forceinline__ unsigned hashf(int flat) {
    return ((unsigned)flat * 2654435761u) >> (32 - HBITS);
}

__device__ __forceinline__ int voxel_flat(float4 pt) {
    // identical IEEE f32 math to reference
    float fx = floorf((pt.x + 51.2f) / 0.1f);
    float fy = floorf((pt.y + 51.2f) / 0.1f);
    float fz = floorf((pt.z + 5.0f) / 0.2f);
    int cx = (int)fx, cy = (int)fy, cz = (int)fz;
    bool valid = (fx >= 0.f) & (cx < GX) & (fy >= 0.f) & (cy < GY) & (fz >= 0.f) & (cz < GZ);
    return valid ? (cx * GY + cy) * GZ + cz : -1;
}

// ---- exact insert path (R12 semantics): 1 CAS typ.; returns pflat value ----
__device__ __forceinline__ int build_insert(int p, int flat, u64* __restrict__ h64,
                                            unsigned char* __restrict__ contested,
                                            int* __restrict__ nvox,
                                            unsigned* __restrict__ bitmap,
                                            int count_wins) {
    u64 want = ((u64)(unsigned)flat << 32) | (unsigned)p;
    unsigned slot = hashf(flat);
    int cand = 0, won = 0;
    for (int probe = 0; probe < 4096; probe++) {          // bounded: hang-proof
        u64 cur = atomicCAS(&h64[slot], EMPTY64, want);
        if (cur == EMPTY64) { cand = 1; won = 1; break; } // insert winner (new voxel)
        if ((unsigned)(cur >> 32) == (unsigned)flat) {    // existing voxel
            if ((unsigned)cur > (unsigned)p) {
                u64 old = atomicMin(&h64[slot], want);    // key equal -> compares rep
                unsigned oldrep = (unsigned)old;
                if (oldrep > (unsigned)p) {               // we really lowered it
                    contested[oldrep] = 1;                // previous holder dethroned
                    cand = 1;
                }
            }
            break;
        }
        slot = (slot + 1u) & HMASK;
    }
    if (won) {
        atomicOr(&bitmap[(unsigned)flat >> 5], 1u << (flat & 31));  // voxel present
        if (count_wins) atomicAdd(nvox, 1);               // wave-aggregated
    }
    return flat | (cand ? CANDBIT : 0);
}

// ---- dup registration: flat -> h64 rep -> popcount rank -> dupcnt/list ----
__device__ __forceinline__ void register_dup(int flat, int i,
                                             const u64* __restrict__ h64,
                                             const u64* __restrict__ flagbits,
                                             const int* __restrict__ partials,
                                             int* __restrict__ dupcnt,
                                             int* __restrict__ list) {
    unsigned slot = hashf(flat);
    unsigned rep = 0xFFFFFFFFu;
    for (int probe = 0; probe < 4096; probe++) {     // read-only, 2MB = L2/L3-hot
        u64 cur = h64[slot];
        if ((unsigned)(cur >> 32) == (unsigned)flat) { rep = (unsigned)cur; break; }
        if (cur == EMPTY64) break;
        slot = (slot + 1u) & HMASK;
    }
    if (rep == 0xFFFFFFFFu) return;
    int br = (int)(rep >> 8);                        // rep's 256-block
    int lb = (int)(rep & 255u);
    int dvid = partials[br];
    int wb = br * 4, nw = lb >> 6;
    for (int q = 0; q < nw; q++) dvid += (int)__popcll(flagbits[wb + q]);
    int tail = lb & 63;
    if (tail) dvid += (int)__popcll(flagbits[wb + nw] & ((1ull << tail) - 1ull));
    if (dvid < MAXV) {
        int pos = atomicAdd(&dupcnt[dvid], 1);
        if (pos < MAXP - 1) list[dvid * (MAXP - 1) + pos] = i;
    }
}

// ---- single-block exclusive scan over npb partials (+ voxel_num) ----
__device__ __forceinline__ void scan_inline(int* __restrict__ partials, int npb,
                                            float* __restrict__ oF) {
    __shared__ int s2[TB];
    int t = threadIdx.x;
    int E = (npb + TB - 1) / TB;                     // 2 fast / 19 fallback
    int s = 0;
    for (int k = 0; k < E; k++) {
        int idx = t * E + k;
        if (idx < npb) s += partials[idx];
    }
    s2[t] = s;
    __syncthreads();
    for (int off = 1; off < TB; off <<= 1) {
        int add = (t >= off) ? s2[t - off] : 0;
        __syncthreads();
        s2[t] += add;
        __syncthreads();
    }
    int run = s2[t] - s;                             // exclusive base
    for (int k = 0; k < E; k++) {
        int idx = t * E + k;
        if (idx < npb) { int tmp = partials[idx]; partials[idx] = run; run += tmp; }
    }
    if (t == TB - 1) {
        int total = s2[TB - 1];
        if (total > MAXV) total = MAXV;
        oF[OFF_VNUM] = (float)total;                 // voxel_num
    }
}

// ---- fallback-only grid barrier: RMW arrivals + RMW-identity polls (both go
//      to the coherence point; no cache-invalidate storm, no L2 staleness).
//      Grid MIDB=1024 is co-resident at __launch_bounds__(256,4). Bounded. ----
__device__ __forceinline__ void fb_bar(int* __restrict__ ctrl) {
    __shared__ int win;
    __syncthreads();
    if (threadIdx.x == 0) {
        __threadfence();                             // wb prior plain stores
        int c = atomicAdd(&ctrl[16], 1);
        win = (c == MIDB - 1);
    }
    __syncthreads();
    if (win) {
        if (threadIdx.x < NREL) atomicExch(&ctrl[32 + threadIdx.x * 16], 1);
        __syncthreads();
    } else {
        if (threadIdx.x == 0) {
            int* f = &ctrl[32 + (blockIdx.x & (NREL - 1)) * 16];
            for (long sp = 0; sp < (1L << 24); sp++) {   // bounded: hang-proof
                if (atomicAdd(f, 0) != 0) break;         // CP read, cache-neutral
                __builtin_amdgcn_s_sleep(2);
            }
        }
        __syncthreads();
    }
    __threadfence();                                 // inv: see released data
}

// ---- init: h64=EMPTY(2MB), bitmap=0(5.25MB), contested=0, dupcnt=0,
//      repidx=-1, coors=0, partials=0, ctrl=0, nvox/dcnt=0 ----
__global__ void k_init(u64* __restrict__ h64, unsigned char* __restrict__ contested,
                       int* __restrict__ dupcnt, int* __restrict__ repidx,
                       int n, int nbp, float* __restrict__ oF,
                       int* __restrict__ nvox, unsigned* __restrict__ bitmap,
                       unsigned* __restrict__ dcnt, int* __restrict__ ctrl,
                       int* __restrict__ partials) {
    int i = blockIdx.x * blockDim.x + threadIdx.x;
    int stride = gridDim.x * blockDim.x;
    if (i == 0) { *nvox = 0; *dcnt = 0; }
    for (int j = i; j < (int)HSIZE; j += stride) h64[j] = EMPTY64;
    for (int j = i; j < NBITW; j += stride) bitmap[j] = 0u;
    int nw = (n + 3) / 4;
    unsigned* c4 = (unsigned*)contested;
    for (int j = i; j < nw; j += stride) c4[j] = 0;
    for (int j = i; j < MAXV; j += stride) { dupcnt[j] = 0; repidx[j] = -1; }
    for (int j = i; j < MAXV * 3; j += stride) oF[OFF_COORS + j] = 0.f;
    for (int j = i; j < nbp; j += stride) partials[j] = 0;
    for (int j = i; j < 2048; j += stride) ctrl[j] = 0;
}

// ---- build_early: first min(n,KEARLY) pts, full insert + bitmap + count ----
__global__ __launch_bounds__(TB) void k_build_early(const float4* __restrict__ pts, int nE,
                                                    u64* __restrict__ h64,
                                                    int* __restrict__ pflat,
                                                    unsigned char* __restrict__ contested,
                                                    int* __restrict__ nvox,
                                                    unsigned* __restrict__ bitmap) {
    int p = blockIdx.x * blockDim.x + threadIdx.x;
    if (p >= nE) return;
    float4 pt = pts[p];
    int flat = voxel_flat(pt);
    if (flat < 0) { pflat[p] = -1; return; }
    pflat[p] = build_insert(p, flat, h64, contested, nvox, bitmap, 1);
}

// ---- mid: fast mode = {flags-early || late bitmap-probe}, scan by the LAST
//      flags block (ticket atomicAdd; nobody waits). Fallback = exact late
//      inserts -> fb_bar -> flags-all -> scan by last. ----
__global__ __launch_bounds__(TB, 4) void k_mid(const float4* __restrict__ pts,
                                               int n, int nbp,
                                               u64* __restrict__ h64,
                                               unsigned* __restrict__ bitmap,
                                               unsigned char* __restrict__ contested,
                                               int* __restrict__ pflat,
                                               u64* __restrict__ flagbits,
                                               int* __restrict__ partials,
                                               u64* __restrict__ latedup,
                                               int* __restrict__ nvox,
                                               unsigned* __restrict__ dcnt,
                                               int* __restrict__ ctrl,
                                               float* __restrict__ oF) {
    const int b = blockIdx.x, t = threadIdx.x;
    const bool fast = (*nvox >= MAXV);               // prev dispatch: plain read ok
    const int npbF = nbp < NBE ? nbp : NBE;
    __shared__ int ws4[4];
    __shared__ int amLast;

    if (fast) {
        if (b < npbF) {
            // flags for early point-block b (late points can never be reps)
            int i = b * TB + t;
            int pred = 0;
            if (i < n) {
                int pf = pflat[i];
                pred = (pf >= 0) && (pf & CANDBIT) && !contested[i];
            }
            u64 m = __ballot(pred);
            int w = t >> 6;
            if ((t & 63) == 0) { flagbits[b * 4 + w] = m; ws4[w] = __popcll(m); }
            __syncthreads();
            if (t == 0) {
                partials[b] = ws4[0] + ws4[1] + ws4[2] + ws4[3];
                __threadfence();                     // wb flagbits+partials
                int done = atomicAdd(&ctrl[0], 1);   // ticket (CP)
                amLast = (done == npbF - 1);
            }
            __syncthreads();
            if (amLast) {                            // all 511 others arrived first
                __threadfence();                     // inv: fresh partials
                scan_inline(partials, npbF, oF);
            }
        } else {
            // late probe: >=MAXV voxels exist with reps < KEARLY <= p, so a
            // voxel first seen here would get vid >= MAXV => dropped. Only
            // dup-of-early matters; the bitmap answers membership exactly.
            for (int p = KEARLY + (b - NBE) * TB + t; p < n; p += (MIDB - NBE) * TB) {
                float4 pt = pts[p];
                int flat = voxel_flat(pt);
                if (flat < 0) continue;
                unsigned wv = bitmap[(unsigned)flat >> 5];
                if (wv & (1u << (flat & 31))) {
                    unsigned pos = atomicAdd(dcnt, 1u);
                    if (pos < (unsigned)(n - KEARLY))
                        latedup[pos] = ((u64)(unsigned)flat << 32) | (unsigned)p;
                }
            }
        }
        return;
    }

    // ---- fallback (adversarial inputs only): exact R12 semantics ----
    for (int p = KEARLY + b * TB + t; p < n; p += MIDB * TB) {
        float4 pt = pts[p];
        int flat = voxel_flat(pt);
        if (flat < 0) { pflat[p] = -1; continue; }
        pflat[p] = build_insert(p, flat, h64, contested, nvox, bitmap, 0);
    }
    fb_bar(ctrl);                                    // all inserts visible
    for (int pb = b; pb < nbp; pb += MIDB) {         // flags over ALL blocks
        int i = pb * TB + t;
        int pred = 0;
        if (i < n) {
            int pf = pflat[i];
            pred = (pf >= 0) && (pf & CANDBIT) && !contested[i];
        }
        u64 m = __ballot(pred);
        if ((t & 63) == 0) flagbits[pb * 4 + (t >> 6)] = m;
        __syncthreads();
        if (t == 0) {
            int s = (int)__popcll(flagbits[pb * 4 + 0]) + (int)__popcll(flagbits[pb * 4 + 1])
                  + (int)__popcll(flagbits[pb * 4 + 2]) + (int)__popcll(flagbits[pb * 4 + 3]);
            partials[pb] = s;
        }
        __syncthreads();
    }
    __syncthreads();
    if (t == 0) {
        __threadfence();
        int done = atomicAdd(&ctrl[8], 1);
        amLast = (done == MIDB - 1);
    }
    __syncthreads();
    if (amLast) {
        __threadfence();
        scan_inline(partials, nbp, oF);
    }
}

// ---- finish: early blocks per-point (reps->coors/repidx, dups->register);
//      blocks >= NBE drain latedup in fast mode / per-point in fallback ----
__global__ __launch_bounds__(TB) void k_finish(const u64* __restrict__ flagbits,
                                               const int* __restrict__ partials,
                                               const int* __restrict__ pflat,
                                               const u64* __restrict__ h64,
                                               int* __restrict__ repidx,
                                               int* __restrict__ dupcnt,
                                               int* __restrict__ list, int n,
                                               float* __restrict__ oF,
                                               const int* __restrict__ nvox,
                                               const u64* __restrict__ latedup,
                                               const unsigned* __restrict__ dcnt) {
    int b = blockIdx.x, t = threadIdx.x;
    int fastmode = (*nvox >= MAXV);
    if (fastmode && b >= NBE) {                      // drain latedup chunk
        unsigned cnt = *dcnt;
        unsigned cap = (n > KEARLY) ? (unsigned)(n - KEARLY) : 0u;
        if (cnt > cap) cnt = cap;
        unsigned idx = (unsigned)(b - NBE) * TB + t;
        if (idx < cnt) {
            u64 e = latedup[idx];
            register_dup((int)(e >> 32), (int)(unsigned)e,
                         h64, flagbits, partials, dupcnt, list);
        }
        return;
    }
    int i = b * TB + t;
    if (i >= n) return;
    int lane = t & 63, w = t >> 6;
    u64 w0 = flagbits[b * 4 + 0];
    u64 w1 = flagbits[b * 4 + 1];
    u64 w2 = flagbits[b * 4 + 2];
    u64 w3 = flagbits[b * 4 + 3];
    u64 myw = (w == 0) ? w0 : (w == 1) ? w1 : (w == 2) ? w2 : w3;
    int bit = (int)((myw >> lane) & 1);
    int pf = pflat[i];
    if (bit) {                                       // first occurrence (rep)
        int wbase = (w > 0 ? __popcll(w0) : 0) + (w > 1 ? __popcll(w1) : 0)
                  + (w > 2 ? __popcll(w2) : 0);
        int vid = partials[b] + wbase + (int)__popcll(myw & ((1ull << lane) - 1ull));
        if (vid < MAXV) {
            int flat = pf & FLATMASK;
            int zc = flat % GZ;
            int t2 = flat / GZ;
            int yc = t2 % GY;
            int xc = t2 / GY;
            size_t cOff = OFF_COORS + (size_t)vid * 3;
            oF[cOff + 0] = (float)zc;
            oF[cOff + 1] = (float)yc;
            oF[cOff + 2] = (float)xc;
            repidx[vid] = i;
        }
    } else if (pf >= 0) {                            // non-rep valid
        register_dup(pf & FLATMASK, i, h64, flagbits, partials, dupcnt, list);
    }
}

// ---- emit: thread-per-row, fully coalesced voxels store; npv ----
__global__ __launch_bounds__(TB) void k_emit(const float4* __restrict__ pts,
                                             const int* __restrict__ repidx,
                                             const int* __restrict__ dupcnt,
                                             const int* __restrict__ list,
                                             float4* __restrict__ outVox,
                                             float* __restrict__ oF) {
    int gid = blockIdx.x * TB + threadIdx.x;
    int vid = gid >> 5;
    if (vid >= MAXV) return;
    int r = gid & 31;
    int ri = repidx[vid];
    int dc = dupcnt[vid];
    int d = dc < (MAXP - 1) ? dc : (MAXP - 1);
    int m = (ri >= 0) ? (1 + d) : 0;
    if (r == 0) oF[OFF_NPV + vid] = (float)m;
    float4 row = make_float4(0.f, 0.f, 0.f, 0.f);
    if (r == 0 && m > 0) {
        row = pts[ri];                               // rep = provably min index
    } else if (r < m) {                              // dup rows, ascending index
        const int* lst = &list[vid * (MAXP - 1)];
        int target = r - 1, pick = -1;
        for (int a = 0; a < d; a++) {
            int e = lst[a];
            int rk = 0;
            for (int bq = 0; bq < d; bq++) rk += (lst[bq] < e);
            if (rk == target) pick = e;
        }
        row = pts[pick];
    }
    outVox[(size_t)vid * MAXP + r] = row;            // coalesced 16B x 64 lanes
}

extern "C" void kernel_launch(void* const* d_in, const int* in_sizes, int n_in,
                              void* d_out, int out_size, void* d_ws, size_t ws_size,
                              hipStream_t stream) {
    int n = in_sizes[0] / 4;                       // 1,200,000
    const float4* pts = (const float4*)d_in[0];

    int tb = TB;
    int nbp = (n + tb - 1) / tb;                   // 4688
    int nwords = nbp * 4;

    // ws layout, ~30 MB
    char* base = (char*)d_ws;
    size_t o = 0;
    int* partials = (int*)(base + o);  o += ((size_t)nbp * 4 + 255) & ~(size_t)255;
    int* dupcnt   = (int*)(base + o);  o += (size_t)MAXV * 4;
    int* repidx   = (int*)(base + o);  o += (size_t)MAXV * 4;
    o = (o + 255) & ~(size_t)255;
    u64* flagbits = (u64*)(base + o);  o += (size_t)nwords * 8;
    o = (o + 255) & ~(size_t)255;
    unsigned char* contested = (unsigned char*)(base + o);  o += ((size_t)n + 255) & ~(size_t)255;
    u64* h64      = (u64*)(base + o);  o += (size_t)HSIZE * 8;
    int* pflat    = (int*)(base + o);  o += (size_t)n * 4;
    int* list     = (int*)(base + o);  o += (size_t)MAXV * (MAXP - 1) * 4;
    o = (o + 255) & ~(size_t)255;
    unsigned* bitmap = (unsigned*)(base + o);  o += (size_t)NBITW * 4;
    o = (o + 255) & ~(size_t)255;
    u64* latedup  = (u64*)(base + o);  o += (size_t)(n > KEARLY ? n - KEARLY : 1) * 8;
    o = (o + 255) & ~(size_t)255;
    int* nvox     = (int*)(base + o);  o += 256;
    unsigned* dcnt = (unsigned*)(base + o);  o += 256;
    int* ctrl     = (int*)(base + o);  o += 2048 * 4;

    float* oF = (float*)d_out;
    float4* outVox = (float4*)d_out;

    int nE = n < KEARLY ? n : KEARLY;
    int nbE = (nE + tb - 1) / tb;                  // 512

    k_init<<<2048, tb, 0, stream>>>(h64, contested, dupcnt, repidx, n, nbp, oF,
                                    nvox, bitmap, dcnt, ctrl, partials);
    k_build_early<<<nbE, tb, 0, stream>>>(pts, nE, h64, pflat, contested, nvox, bitmap);
    k_mid<<<MIDB, tb, 0, stream>>>(pts, n, nbp, h64, bitmap, contested, pflat,
                                   flagbits, partials, latedup, nvox, dcnt, ctrl, oF);
    k_finish<<<nbp, tb, 0, stream>>>(flagbits, partials, pflat, h64, repidx, dupcnt,
                                     list, n, oF, nvox, latedup, dcnt);
    k_emit<<<(MAXV * MAXP + tb - 1) / tb, tb, 0, stream>>>(pts, repidx, dupcnt, list,
                                                           outVox, oF);
}

// Round 8
// 134.142 us; speedup vs baseline: 3.2037x; 1.1147x over previous
//
#include <hip/hip_runtime.h>
#include <stdint.h>

// Hard voxelization, MI355X. f32x4 points -> f32 concat out:
//   voxels[60000,32,4], coors[60000,3](z,y,x), npv[60000], voxel_num[1].
//
// R20: REVERT to the best-measured configuration (round-1, 136.05us).
// Session forensics: kernel-side savings of ~70us device time (R13 build
// split -40us CAS, R15 bitmap -30us probes) and a 7->5 dispatch merge (R19)
// all left dur_us in [136,150]; in-kernel grid sync (R16-18) regressed 3-6x
// (~100us/sync on gfx950 regardless of ACQUIRE-poll / RELAXED-poll / cg).
// dur_us is harness-floor-dominated: ~45us ws re-poison fill + dispatch
// overhead + ~35-40us kernel work. R19's bundle (k_mid role-split merge,
// HBITS 18) was net -10us regression -> reverted per rigor.md.
//
// Structure (proven): cap-aware build split. Only the first ~100K points can
// create one of the 60000 output voxels (this input: ~734K distinct voxels;
// rep #60000 lands near point ~97K). k_build_early inserts the first 131072
// points (~81K distinct voxels, >100-sigma above cap) counting insert wins
// into nvox. k_build_late sees nvox>=MAXV: table immutable, so late points do
// a READ-ONLY probe (hit => dup via k_finish's re-probe path; miss => vid
// would be >=MAXV => dropped). If nvox<MAXV (adversarial), late falls back to
// the exact R12 insert path - correctness never depends on input statistics.

#define GX 1024
#define GY 1024
#define GZ 40
#define MAXV 60000
#define MAXP 32
#define HBITS 21
#define HSIZE (1u << HBITS)
#define HMASK (HSIZE - 1u)
#define CANDBIT (1 << 30)
#define FLATMASK (CANDBIT - 1)
#define TB 256
#define KEARLY 131072
#define EMPTY64 0xFFFFFFFFFFFFFFFFull

#define OFF_COORS ((size_t)MAXV * MAXP * 4)            // 7,680,000
#define OFF_NPV   (OFF_COORS + (size_t)MAXV * 3)       // 7,860,000
#define OFF_VNUM  (OFF_NPV + (size_t)MAXV)             // 7,920,000

typedef unsigned long long u64;

__device__ __forceinline__ unsigned hashf(int flat) {
    return ((unsigned)flat * 2654435761u) >> (32 - HBITS);
}

// ---- init: h64=EMPTY(16MB), contested=0, dupcnt=0, repidx=-1, coors=0 ----
__global__ void k_init(u64* __restrict__ h64, unsigned char* __restrict__ contested,
                       int* __restrict__ dupcnt, int* __restrict__ repidx,
                       int n, float* __restrict__ oF, int* __restrict__ nvox) {
    int i = blockIdx.x * blockDim.x + threadIdx.x;
    int stride = gridDim.x * blockDim.x;
    if (i == 0) *nvox = 0;
    for (int j = i; j < (int)HSIZE; j += stride) h64[j] = EMPTY64;
    int nw = (n + 3) / 4;
    unsigned* c4 = (unsigned*)contested;
    for (int j = i; j < nw; j += stride) c4[j] = 0;
    for (int j = i; j < MAXV; j += stride) { dupcnt[j] = 0; repidx[j] = -1; }
    for (int j = i; j < MAXV * 3; j += stride) oF[OFF_COORS + j] = 0.f;
}

__device__ __forceinline__ int voxel_flat(float4 pt) {
    // identical IEEE f32 math to reference
    float fx = floorf((pt.x + 51.2f) / 0.1f);
    float fy = floorf((pt.y + 51.2f) / 0.1f);
    float fz = floorf((pt.z + 5.0f) / 0.2f);
    int cx = (int)fx, cy = (int)fy, cz = (int)fz;
    bool valid = (fx >= 0.f) & (cx < GX) & (fy >= 0.f) & (cy < GY) & (fz >= 0.f) & (cz < GZ);
    return valid ? (cx * GY + cy) * GZ + cz : -1;
}

// ---- exact insert path (R12 semantics): 1 CAS typ.; returns pflat value ----
__device__ __forceinline__ int build_insert(int p, int flat, u64* __restrict__ h64,
                                            unsigned char* __restrict__ contested,
                                            int* __restrict__ nvox, int count_wins) {
    u64 want = ((u64)(unsigned)flat << 32) | (unsigned)p;
    unsigned slot = hashf(flat);
    int cand = 0, won = 0;
    for (int probe = 0; probe < 4096; probe++) {          // bounded: hang-proof
        u64 cur = atomicCAS(&h64[slot], EMPTY64, want);
        if (cur == EMPTY64) { cand = 1; won = 1; break; } // insert winner (new voxel)
        if ((unsigned)(cur >> 32) == (unsigned)flat) {    // existing voxel
            if ((unsigned)cur > (unsigned)p) {
                u64 old = atomicMin(&h64[slot], want);    // key equal -> compares rep
                unsigned oldrep = (unsigned)old;
                if (oldrep > (unsigned)p) {               // we really lowered it
                    contested[oldrep] = 1;                // previous holder dethroned
                    cand = 1;
                }
            }
            break;
        }
        slot = (slot + 1u) & HMASK;
    }
    if (count_wins && won) atomicAdd(nvox, 1);            // wave-aggregated by compiler
    return flat | (cand ? CANDBIT : 0);
}

// ---- build A: first nE points, full insert + distinct-voxel count ----
__global__ __launch_bounds__(TB) void k_build_early(const float4* __restrict__ pts, int nE,
                                                    u64* __restrict__ h64,
                                                    int* __restrict__ pflat,
                                                    unsigned char* __restrict__ contested,
                                                    int* __restrict__ nvox) {
    int p = blockIdx.x * blockDim.x + threadIdx.x;
    if (p >= nE) return;
    float4 pt = pts[p];
    int flat = voxel_flat(pt);
    if (flat < 0) { pflat[p] = -1; return; }
    pflat[p] = build_insert(p, flat, h64, contested, nvox, 1);
}

// ---- build B: points [KEARLY, n). Fast path (cap reached): read-only probe,
//      table immutable -> cacheable, no atomics. Slow path: exact insert. ----
__global__ __launch_bounds__(TB) void k_build_late(const float4* __restrict__ pts, int n,
                                                   u64* __restrict__ h64,
                                                   int* __restrict__ pflat,
                                                   unsigned char* __restrict__ contested,
                                                   int* __restrict__ nvox) {
    int p = KEARLY + blockIdx.x * blockDim.x + threadIdx.x;
    if (p >= n) return;
    float4 pt = pts[p];
    int flat = voxel_flat(pt);
    if (flat < 0) { pflat[p] = -1; return; }
    if (*nvox >= MAXV) {
        // >=MAXV voxels already exist with reps < KEARLY <= p: any voxel first
        // seen here would rank >= MAXV => dropped. Only dup-of-early matters.
        unsigned slot = hashf(flat);
        int out = -1;
        for (int probe = 0; probe < 4096; probe++) {      // read-only, table-hot
            u64 cur = h64[slot];
            if (cur == EMPTY64) break;                    // new voxel -> dropped
            if ((unsigned)(cur >> 32) == (unsigned)flat) { out = flat; break; } // dup
            slot = (slot + 1u) & HMASK;
        }
        pflat[p] = out;                                   // flat (no CANDBIT) or -1
        return;
    }
    pflat[p] = build_insert(p, flat, h64, contested, nvox, 0);   // exact fallback
}

// ---- flags: 1 pt/thread; ballot -> flag word + block sum. No loops. ----
__global__ __launch_bounds__(TB) void k_flags(const int* __restrict__ pflat,
                                              const unsigned char* __restrict__ contested,
                                              int n, u64* __restrict__ flagbits,
                                              int* __restrict__ partials) {
    __shared__ int ws[4];
    int b = blockIdx.x, t = threadIdx.x;
    int i = b * TB + t;
    int pred = 0;
    if (i < n) {
        int pf = pflat[i];
        pred = (pf >= 0) && (pf & CANDBIT) && !contested[i];
    }
    u64 m = __ballot(pred);
    int w = t >> 6, lane = t & 63;
    if (lane == 0) { flagbits[b * 4 + w] = m; ws[w] = __popcll(m); }
    __syncthreads();
    if (t == 0) partials[b] = ws[0] + ws[1] + ws[2] + ws[3];
}

// ---- scan: one 1024-thread block, 5 partials/thread -> exclusive offsets ----
__global__ __launch_bounds__(1024) void k_scan(int* __restrict__ partials, int npart,
                                               float* __restrict__ oF) {
    __shared__ int sh[1024];
    int t = threadIdx.x;
    int v[5];
    int s = 0;
    #pragma unroll
    for (int k = 0; k < 5; k++) {
        int idx = t * 5 + k;
        v[k] = (idx < npart) ? partials[idx] : 0;
        s += v[k];
    }
    sh[t] = s;
    __syncthreads();
    for (int off = 1; off < 1024; off <<= 1) {
        int add = (t >= off) ? sh[t - off] : 0;
        __syncthreads();
        sh[t] += add;
        __syncthreads();
    }
    int run = sh[t] - s;                     // exclusive base for this thread
    #pragma unroll
    for (int k = 0; k < 5; k++) {
        int idx = t * 5 + k;
        if (idx < npart) partials[idx] = run;
        run += v[k];
    }
    if (t == 1023) {
        int total = sh[1023];
        if (total > MAXV) total = MAXV;
        oF[OFF_VNUM] = (float)total;         // voxel_num
    }
}

// ---- finish: 1 pt/thread; vid via popcount rank; reps->coors/repidx,
//      dups(~9K)->h64 re-probe + rank -> dupcnt/list ----
__global__ __launch_bounds__(TB) void k_finish(const u64* __restrict__ flagbits,
                                               const int* __restrict__ partials,
                                               const int* __restrict__ pflat,
                                               const u64* __restrict__ h64,
                                               int* __restrict__ repidx,
                                               int* __restrict__ dupcnt,
                                               int* __restrict__ list, int n,
                                               float* __restrict__ oF) {
    int b = blockIdx.x, t = threadIdx.x;
    int i = b * TB + t;
    if (i >= n) return;
    int lane = t & 63, w = t >> 6;
    u64 w0 = flagbits[b * 4 + 0];
    u64 w1 = flagbits[b * 4 + 1];
    u64 w2 = flagbits[b * 4 + 2];
    u64 w3 = flagbits[b * 4 + 3];
    u64 myw = (w == 0) ? w0 : (w == 1) ? w1 : (w == 2) ? w2 : w3;
    int bit = (int)((myw >> lane) & 1);
    int pf = pflat[i];
    if (bit) {                                           // first occurrence (rep)
        int wbase = (w > 0 ? __popcll(w0) : 0) + (w > 1 ? __popcll(w1) : 0)
                  + (w > 2 ? __popcll(w2) : 0);
        int vid = partials[b] + wbase + (int)__popcll(myw & ((1ull << lane) - 1ull));
        if (vid < MAXV) {
            int flat = pf & FLATMASK;
            int zc = flat % GZ;
            int t2 = flat / GZ;
            int yc = t2 % GY;
            int xc = t2 / GY;
            size_t cOff = OFF_COORS + (size_t)vid * 3;
            oF[cOff + 0] = (float)zc;
            oF[cOff + 1] = (float)yc;
            oF[cOff + 2] = (float)xc;
            repidx[vid] = i;
        }
    } else if (pf >= 0) {                                // non-rep valid (~9K)
        int flat = pf & FLATMASK;
        unsigned slot = hashf(flat);
        unsigned rep = 0xFFFFFFFFu;
        for (int probe = 0; probe < 4096; probe++) {     // read-only, L3-hot
            u64 cur = h64[slot];
            if ((unsigned)(cur >> 32) == (unsigned)flat) { rep = (unsigned)cur; break; }
            if (cur == EMPTY64) break;
            slot = (slot + 1u) & HMASK;
        }
        if (rep != 0xFFFFFFFFu) {
            int br = (int)(rep >> 8);                    // rep's 256-block
            int lb = (int)(rep & 255u);
            int dvid = partials[br];
            int wb = br * 4, nw = lb >> 6;
            for (int q = 0; q < nw; q++) dvid += (int)__popcll(flagbits[wb + q]);
            int tail = lb & 63;
            if (tail) dvid += (int)__popcll(flagbits[wb + nw] & ((1ull << tail) - 1ull));
            if (dvid < MAXV) {
                int pos = atomicAdd(&dupcnt[dvid], 1);
                if (pos < MAXP - 1) list[dvid * (MAXP - 1) + pos] = i;
            }
        }
    }
}

// ---- emit: thread-per-row, fully coalesced voxels store; npv ----
__global__ __launch_bounds__(TB) void k_emit(const float4* __restrict__ pts,
                                             const int* __restrict__ repidx,
                                             const int* __restrict__ dupcnt,
                                             const int* __restrict__ list,
                                             float4* __restrict__ outVox,
                                             float* __restrict__ oF) {
    int gid = blockIdx.x * TB + threadIdx.x;
    int vid = gid >> 5;
    if (vid >= MAXV) return;
    int r = gid & 31;
    int ri = repidx[vid];
    int dc = dupcnt[vid];
    int d = dc < (MAXP - 1) ? dc : (MAXP - 1);
    int m = (ri >= 0) ? (1 + d) : 0;
    if (r == 0) oF[OFF_NPV + vid] = (float)m;
    float4 row = make_float4(0.f, 0.f, 0.f, 0.f);
    if (r == 0 && m > 0) {
        row = pts[ri];                               // rep = provably min index
    } else if (r < m) {                              // dup rows, ascending index
        const int* lst = &list[vid * (MAXP - 1)];
        int target = r - 1, pick = -1;
        for (int a = 0; a < d; a++) {
            int e = lst[a];
            int rk = 0;
            for (int bq = 0; bq < d; bq++) rk += (lst[bq] < e);
            if (rk == target) pick = e;
        }
        row = pts[pick];
    }
    outVox[(size_t)vid * MAXP + r] = row;            // coalesced 16B x 64 lanes
}

extern "C" void kernel_launch(void* const* d_in, const int* in_sizes, int n_in,
                              void* d_out, int out_size, void* d_ws, size_t ws_size,
                              hipStream_t stream) {
    int n = in_sizes[0] / 4;                       // 1,200,000
    const float4* pts = (const float4*)d_in[0];

    int tb = TB;
    int nbp = (n + tb - 1) / tb;                   // 4688 (1 pt/thread grids)
    int nwords = nbp * 4;                          // flag words (4 per block)

    // ws layout, ~30 MB
    char* base = (char*)d_ws;
    size_t o = 0;
    int* partials = (int*)(base + o);  o += ((size_t)nbp * 4 + 255) & ~(size_t)255;
    int* dupcnt   = (int*)(base + o);  o += (size_t)MAXV * 4;
    int* repidx   = (int*)(base + o);  o += (size_t)MAXV * 4;
    o = (o + 255) & ~(size_t)255;
    u64* flagbits = (u64*)(base + o);  o += (size_t)nwords * 8;
    o = (o + 255) & ~(size_t)255;
    unsigned char* contested = (unsigned char*)(base + o);  o += ((size_t)n + 255) & ~(size_t)255;
    u64* h64      = (u64*)(base + o);  o += (size_t)HSIZE * 8;
    int* pflat    = (int*)(base + o);  o += (size_t)n * 4;
    int* list     = (int*)(base + o);  o += (size_t)MAXV * (MAXP - 1) * 4;
    o = (o + 255) & ~(size_t)255;
    int* nvox     = (int*)(base + o);  o += 256;

    float* oF = (float*)d_out;

    int nE = n < KEARLY ? n : KEARLY;
    int nbE = (nE + tb - 1) / tb;                  // 512
    int nL = n - nE;

    k_init<<<2048, tb, 0, stream>>>(h64, contested, dupcnt, repidx, n, oF, nvox);
    k_build_early<<<nbE, tb, 0, stream>>>(pts, nE, h64, pflat, contested, nvox);
    if (nL > 0)
        k_build_late<<<(nL + tb - 1) / tb, tb, 0, stream>>>(pts, n, h64, pflat,
                                                            contested, nvox);
    k_flags<<<nbp, tb, 0, stream>>>(pflat, contested, n, flagbits, partials);
    k_scan<<<1, 1024, 0, stream>>>(partials, nbp, oF);
    k_finish<<<nbp, tb, 0, stream>>>(flagbits, partials, pflat, h64, repidx, dupcnt, list, n, oF);
    k_emit<<<(MAXV * MAXP + tb - 1) / tb, tb, 0, stream>>>(pts, repidx, dupcnt, list,
                                                           (float4*)d_out, oF);
}